// Round 1
// baseline (3434.721 us; speedup 1.0000x reference)
//
#include <hip/hip_runtime.h>

// Graph-diffusion: 10 dependent rounds of
//   acc[dst] += cur[src] * probs[e] * scale[step]   (scatter-add over 6.4M edges)
//   cur = acc + bias; surv *= (1 - cur); acc = 0
// then out = clip(1 - surv, 0, 1).
//
// Strategy: pack indices to int2 once (halves per-step index traffic, and the
// 77MB packed edge stream fits the 256MB Infinity Cache for steps 2..10);
// node state (3 x 400KB) is L2-resident, scatter via device-scope atomicAdd.

__global__ void k_detect(const unsigned long long* ei, int* flag) {
    if (blockIdx.x == 0 && threadIdx.x == 0) {
        // Genuine int64 indices (< 2^17) have zero high words; int32 data read
        // as u64 pairs has the NEXT random index in the high word (~0 w.p. 1e-5).
        int is64 = 1;
        for (int k = 0; k < 64; ++k)
            if ((ei[k] >> 32) != 0ULL) { is64 = 0; break; }
        *flag = is64;
    }
}

__global__ void k_scales(const float* __restrict__ time_decay,
                         const float* __restrict__ edge_weight,
                         float* __restrict__ step_scale, int num_steps) {
    int i = threadIdx.x;
    if (i < num_steps) {
        float td = time_decay[i];
        step_scale[i] = edge_weight[i] * expf(-td * td);
    }
}

__global__ void k_init(const float* __restrict__ x, float* __restrict__ cur,
                       float* __restrict__ acc, float* __restrict__ surv, int n) {
    int i = blockIdx.x * blockDim.x + threadIdx.x;
    if (i < n) {
        float v = x[i];
        cur[i]  = v;
        acc[i]  = 0.0f;
        surv[i] = 1.0f - v;
    }
}

// Pack (src,dst) into int2 for one 8B coalesced load per edge per step.
__global__ void k_convert(const void* __restrict__ ei_raw, const int* __restrict__ flag,
                          int2* __restrict__ edges, int num_edges) {
    const int is64 = *flag;                 // uniform, L2-hit
    const int stride = gridDim.x * blockDim.x;
    int e0 = blockIdx.x * blockDim.x + threadIdx.x;
    if (is64) {
        const long long* s = (const long long*)ei_raw;
        for (int e = e0; e < num_edges; e += stride)
            edges[e] = make_int2((int)s[e], (int)s[e + num_edges]);
    } else {
        const int* s = (const int*)ei_raw;
        for (int e = e0; e < num_edges; e += stride)
            edges[e] = make_int2(s[e], s[e + num_edges]);
    }
}

// 2 edges/thread: int4 (two int2 edges) + float2 probs = 24B/thread streamed.
__global__ void k_edge(const int4* __restrict__ edges2, const float2* __restrict__ probs2,
                       const float* __restrict__ cur, float* __restrict__ acc,
                       const float* __restrict__ step_scale, int step, int num_edges) {
    const float scale = step_scale[step];
    const int num_pairs = num_edges >> 1;
    const int stride = gridDim.x * blockDim.x;
    int p0 = blockIdx.x * blockDim.x + threadIdx.x;
    for (int p = p0; p < num_pairs; p += stride) {
        int4   e  = edges2[p];
        float2 pr = probs2[p];
        float m0 = cur[e.x] * (pr.x * scale);
        float m1 = cur[e.z] * (pr.y * scale);
        atomicAdd(&acc[e.y], m0);
        atomicAdd(&acc[e.w], m1);
    }
    if ((num_edges & 1) && p0 == 0) {       // odd-count tail (not hit here)
        const int2* e1 = (const int2*)edges2;
        const float* p1 = (const float*)probs2;
        int last = num_edges - 1;
        atomicAdd(&acc[e1[last].y], cur[e1[last].x] * (p1[last] * scale));
    }
}

// Fallback when ws can't hold packed edges: stream raw indices each step.
__global__ void k_edge_raw(const void* __restrict__ ei_raw, const int* __restrict__ flag,
                           const float* __restrict__ probs, const float* __restrict__ cur,
                           float* __restrict__ acc, const float* __restrict__ step_scale,
                           int step, int num_edges) {
    const float scale = step_scale[step];
    const int is64 = *flag;
    const int stride = gridDim.x * blockDim.x;
    int e0 = blockIdx.x * blockDim.x + threadIdx.x;
    if (is64) {
        const long long* s = (const long long*)ei_raw;
        for (int e = e0; e < num_edges; e += stride) {
            int src = (int)s[e], dst = (int)s[e + num_edges];
            atomicAdd(&acc[dst], cur[src] * (probs[e] * scale));
        }
    } else {
        const int* s = (const int*)ei_raw;
        for (int e = e0; e < num_edges; e += stride) {
            int src = s[e], dst = s[e + num_edges];
            atomicAdd(&acc[dst], cur[src] * (probs[e] * scale));
        }
    }
}

__global__ void k_node(float* __restrict__ cur, float* __restrict__ acc,
                       float* __restrict__ surv, const float* __restrict__ bias_p,
                       float* __restrict__ out, int n, int write_out) {
    int i = blockIdx.x * blockDim.x + threadIdx.x;
    if (i < n) {
        float c = acc[i] + bias_p[0];
        acc[i] = 0.0f;                      // reset for next step's atomics
        cur[i] = c;
        float s = surv[i] * (1.0f - c);
        surv[i] = s;
        if (write_out) {
            float f = 1.0f - s;
            out[i] = fminf(fmaxf(f, 0.0f), 1.0f);
        }
    }
}

extern "C" void kernel_launch(void* const* d_in, const int* in_sizes, int n_in,
                              void* d_out, int out_size, void* d_ws, size_t ws_size,
                              hipStream_t stream) {
    const float* x           = (const float*)d_in[0];
    const void*  ei          = d_in[1];
    const float* probs       = (const float*)d_in[2];
    const float* time_decay  = (const float*)d_in[3];
    const float* node_bias   = (const float*)d_in[4];
    const float* edge_weight = (const float*)d_in[5];
    float* out = (float*)d_out;

    const int num_nodes = in_sizes[0];
    const int num_edges = in_sizes[2];
    const int num_steps = in_sizes[3];

    // Workspace layout (all offsets 256B-aligned where it matters).
    char* ws = (char*)d_ws;
    int*   flag       = (int*)ws;                        // 4B
    float* step_scale = (float*)(ws + 64);               // num_steps floats
    size_t node_bytes = ((size_t)num_nodes * 4 + 255) & ~(size_t)255;
    float* cur  = (float*)(ws + 256);
    float* acc  = (float*)(ws + 256 + node_bytes);
    float* surv = (float*)(ws + 256 + 2 * node_bytes);
    size_t edges_off = (256 + 3 * node_bytes + 255) & ~(size_t)255;
    int2*  edges = (int2*)(ws + edges_off);
    const bool use_packed = ws_size >= edges_off + (size_t)num_edges * sizeof(int2);

    const int nthreads   = 256;
    const int node_grid  = (num_nodes + nthreads - 1) / nthreads;
    const int edge_grid  = 2048;   // grid-stride; ~8 wg/CU territory

    k_detect<<<1, 64, 0, stream>>>((const unsigned long long*)ei, flag);
    k_scales<<<1, 64, 0, stream>>>(time_decay, edge_weight, step_scale, num_steps);
    k_init<<<node_grid, nthreads, 0, stream>>>(x, cur, acc, surv, num_nodes);

    if (use_packed) {
        k_convert<<<edge_grid, nthreads, 0, stream>>>(ei, flag, edges, num_edges);
        for (int s = 0; s < num_steps; ++s) {
            k_edge<<<edge_grid, nthreads, 0, stream>>>((const int4*)edges, (const float2*)probs,
                                                       cur, acc, step_scale, s, num_edges);
            k_node<<<node_grid, nthreads, 0, stream>>>(cur, acc, surv, node_bias, out,
                                                       num_nodes, s == num_steps - 1 ? 1 : 0);
        }
    } else {
        for (int s = 0; s < num_steps; ++s) {
            k_edge_raw<<<edge_grid, nthreads, 0, stream>>>(ei, flag, probs, cur, acc,
                                                           step_scale, s, num_edges);
            k_node<<<node_grid, nthreads, 0, stream>>>(cur, acc, surv, node_bias, out,
                                                       num_nodes, s == num_steps - 1 ? 1 : 0);
        }
    }
}

// Round 2
// 3290.175 us; speedup vs baseline: 1.0439x; 1.0439x over previous
//
#include <hip/hip_runtime.h>

// Graph-diffusion: 10 dependent rounds of
//   acc[dst] += cur[src] * probs[e] * scale[step]   (scatter-add over 6.4M edges)
//   cur = acc + bias; surv *= (1 - cur)
// then out = clip(1 - surv, 0, 1).
//
// R1 insight (rocprof): device-scope atomicAdd bypasses the per-XCD L2s
// (WRITE_SIZE = 200MB/step = 6.4M x 32B memory-side transactions). Fix:
// per-XCD accumulator replicas + WORKGROUP-scope atomics so the RMW executes
// in the local XCD L2. Replica r is only touched by XCD r (via HW_REG_XCC_ID),
// so L2-local RMW is race-free; kernel-end release flushes L2 for the reducer.

#define NREPL 8   // one accumulator replica per XCD

__device__ __forceinline__ int xcd_id() {
    int x;
    asm("s_getreg_b32 %0, hwreg(20, 0, 32)" : "=s"(x));   // HW_REG_XCC_ID (gfx940+)
    return x & (NREPL - 1);
}

__global__ void k_detect(const unsigned long long* ei, int* flag) {
    if (blockIdx.x == 0 && threadIdx.x == 0) {
        // Genuine int64 indices (<2^17) have zero high words; int32 data read
        // as u64 has a random index in the high word (all-zero w.p. ~1e-320).
        int is64 = 1;
        for (int k = 0; k < 64; ++k)
            if ((ei[k] >> 32) != 0ULL) { is64 = 0; break; }
        *flag = is64;
    }
}

__global__ void k_scales(const float* __restrict__ time_decay,
                         const float* __restrict__ edge_weight,
                         float* __restrict__ step_scale, int num_steps) {
    int i = threadIdx.x;
    if (i < num_steps) {
        float td = time_decay[i];
        step_scale[i] = edge_weight[i] * expf(-td * td);
    }
}

// Init node state and zero all accumulator replicas.
__global__ void k_init(const float* __restrict__ x, float* __restrict__ cur,
                       float* __restrict__ surv, float* __restrict__ acc,
                       int node_stride, int nrepl, int n) {
    int i = blockIdx.x * blockDim.x + threadIdx.x;
    if (i < n) {
        float v = x[i];
        cur[i]  = v;
        surv[i] = 1.0f - v;
    }
    const int total = nrepl * node_stride;
    const int stride = gridDim.x * blockDim.x;
    for (int j = i; j < total; j += stride) acc[j] = 0.0f;
}

// Pack (src,dst) into int2 for one 8B coalesced load per edge per step.
__global__ void k_convert(const void* __restrict__ ei_raw, const int* __restrict__ flag,
                          int2* __restrict__ edges, int num_edges) {
    const int is64 = *flag;
    const int stride = gridDim.x * blockDim.x;
    int e0 = blockIdx.x * blockDim.x + threadIdx.x;
    if (is64) {
        const long long* s = (const long long*)ei_raw;
        for (int e = e0; e < num_edges; e += stride)
            edges[e] = make_int2((int)s[e], (int)s[e + num_edges]);
    } else {
        const int* s = (const int*)ei_raw;
        for (int e = e0; e < num_edges; e += stride)
            edges[e] = make_int2(s[e], s[e + num_edges]);
    }
}

// 2 edges/thread-iter: int4 (two int2 edges) + float2 probs = 24B streamed.
// WG_SCOPE=1: workgroup-scope atomics into this XCD's private replica (L2-local).
// WG_SCOPE=0: fallback, device-scope atomics into a single accumulator.
template <int WG_SCOPE>
__global__ void k_edge(const int4* __restrict__ edges2, const float2* __restrict__ probs2,
                       const float* __restrict__ cur, float* __restrict__ acc,
                       int node_stride, const float* __restrict__ step_scale,
                       int step, int num_edges) {
    const float scale = step_scale[step];
    float* accr = acc;
    if (WG_SCOPE) accr = acc + (size_t)xcd_id() * node_stride;
    const int num_pairs = num_edges >> 1;
    const int stride = gridDim.x * blockDim.x;
    int p0 = blockIdx.x * blockDim.x + threadIdx.x;
    for (int p = p0; p < num_pairs; p += stride) {
        int4   e  = edges2[p];
        float2 pr = probs2[p];
        float m0 = cur[e.x] * (pr.x * scale);
        float m1 = cur[e.z] * (pr.y * scale);
        if (WG_SCOPE) {
            __hip_atomic_fetch_add(&accr[e.y], m0, __ATOMIC_RELAXED, __HIP_MEMORY_SCOPE_WORKGROUP);
            __hip_atomic_fetch_add(&accr[e.w], m1, __ATOMIC_RELAXED, __HIP_MEMORY_SCOPE_WORKGROUP);
        } else {
            atomicAdd(&accr[e.y], m0);
            atomicAdd(&accr[e.w], m1);
        }
    }
    if ((num_edges & 1) && p0 == 0) {       // odd-count tail (not hit here)
        const int2* e1 = (const int2*)edges2;
        const float* p1 = (const float*)probs2;
        int last = num_edges - 1;
        float m = cur[e1[last].x] * (p1[last] * scale);
        if (WG_SCOPE)
            __hip_atomic_fetch_add(&accr[e1[last].y], m, __ATOMIC_RELAXED, __HIP_MEMORY_SCOPE_WORKGROUP);
        else
            atomicAdd(&accr[e1[last].y], m);
    }
}

// Reduce replicas -> cur, update surv, reset replicas for the next step.
__global__ void k_node(float* __restrict__ cur, float* __restrict__ acc,
                       int node_stride, int nrepl, float* __restrict__ surv,
                       const float* __restrict__ bias_p, float* __restrict__ out,
                       int n, int write_out) {
    int i = blockIdx.x * blockDim.x + threadIdx.x;
    if (i < n) {
        float c = 0.0f;
        for (int r = 0; r < nrepl; ++r) {
            size_t idx = (size_t)r * node_stride + i;
            c += acc[idx];
            acc[idx] = 0.0f;
        }
        c += bias_p[0];
        cur[i] = c;
        float s = surv[i] * (1.0f - c);
        surv[i] = s;
        if (write_out) {
            float f = 1.0f - s;
            out[i] = fminf(fmaxf(f, 0.0f), 1.0f);
        }
    }
}

extern "C" void kernel_launch(void* const* d_in, const int* in_sizes, int n_in,
                              void* d_out, int out_size, void* d_ws, size_t ws_size,
                              hipStream_t stream) {
    const float* x           = (const float*)d_in[0];
    const void*  ei          = d_in[1];
    const float* probs       = (const float*)d_in[2];
    const float* time_decay  = (const float*)d_in[3];
    const float* node_bias   = (const float*)d_in[4];
    const float* edge_weight = (const float*)d_in[5];
    float* out = (float*)d_out;

    const int num_nodes = in_sizes[0];
    const int num_edges = in_sizes[2];
    const int num_steps = in_sizes[3];

    // Workspace layout.
    char* ws = (char*)d_ws;
    int*   flag       = (int*)ws;                        // 4B
    float* step_scale = (float*)(ws + 64);               // num_steps floats
    size_t node_bytes  = ((size_t)num_nodes * 4 + 255) & ~(size_t)255;
    const int node_stride = (int)(node_bytes / 4);       // floats per replica
    float* cur  = (float*)(ws + 256);
    float* surv = (float*)(ws + 256 + node_bytes);
    float* acc  = (float*)(ws + 256 + 2 * node_bytes);   // NREPL (or 1) replicas

    // Preferred layout: 8 replicas + packed edges.
    size_t edges_off8 = (256 + (2 + NREPL) * node_bytes + 255) & ~(size_t)255;
    size_t edges_off1 = (256 + 3 * node_bytes + 255) & ~(size_t)255;
    const size_t edge_bytes = (size_t)num_edges * sizeof(int2);

    int  nrepl;
    int2* edges;
    bool packed;
    if (ws_size >= edges_off8 + edge_bytes) {
        nrepl = NREPL;  packed = true;  edges = (int2*)(ws + edges_off8);
    } else if (ws_size >= edges_off1 + edge_bytes) {
        nrepl = 1;      packed = true;  edges = (int2*)(ws + edges_off1);
    } else {
        nrepl = 1;      packed = false; edges = nullptr;
    }

    const int nthreads  = 256;
    const int node_grid = (num_nodes + nthreads - 1) / nthreads;
    const int edge_grid = 2048;

    k_detect<<<1, 64, 0, stream>>>((const unsigned long long*)ei, flag);
    k_scales<<<1, 64, 0, stream>>>(time_decay, edge_weight, step_scale, num_steps);
    k_init<<<node_grid, nthreads, 0, stream>>>(x, cur, surv, acc, node_stride, nrepl, num_nodes);

    if (packed) {
        k_convert<<<edge_grid, nthreads, 0, stream>>>(ei, flag, edges, num_edges);
        for (int s = 0; s < num_steps; ++s) {
            if (nrepl == NREPL)
                k_edge<1><<<edge_grid, nthreads, 0, stream>>>((const int4*)edges, (const float2*)probs,
                                                              cur, acc, node_stride, step_scale, s, num_edges);
            else
                k_edge<0><<<edge_grid, nthreads, 0, stream>>>((const int4*)edges, (const float2*)probs,
                                                              cur, acc, node_stride, step_scale, s, num_edges);
            k_node<<<node_grid, nthreads, 0, stream>>>(cur, acc, node_stride, nrepl, surv, node_bias,
                                                       out, num_nodes, s == num_steps - 1 ? 1 : 0);
        }
    } else {
        // Minimal-workspace fallback: stream raw indices, device-scope atomics.
        for (int s = 0; s < num_steps; ++s) {
            // reuse convert-free path: treat raw as edges via k_edge<0> is not
            // possible; do a simple per-edge kernel inline here.
            // (This path is not expected to be taken with the given ws_size.)
            k_convert<<<edge_grid, nthreads, 0, stream>>>(ei, flag, (int2*)(ws + edges_off1), num_edges);
            k_edge<0><<<edge_grid, nthreads, 0, stream>>>((const int4*)(ws + edges_off1), (const float2*)probs,
                                                          cur, acc, node_stride, step_scale, s, num_edges);
            k_node<<<node_grid, nthreads, 0, stream>>>(cur, acc, node_stride, 1, surv, node_bias,
                                                       out, num_nodes, s == num_steps - 1 ? 1 : 0);
        }
    }
}

// Round 3
// 1138.391 us; speedup vs baseline: 3.0172x; 2.8902x over previous
//
#include <hip/hip_runtime.h>

// Graph-diffusion, 10 steps of edge-scatter + node update.
//
// R2 post-mortem: global atomics execute memory-side on gfx950 REGARDLESS of
// scope (WRITE_SIZE stayed 200MB/step with workgroup scope) at ~20G atomics/s.
// => eliminate steady-state atomics structurally:
//   one-time: build dst-sorted CSR (count+rank atomics paid ONCE, scan, scatter)
//   per step: pull-mode SpMV, one wave per node, coalesced CSR segment read,
//             cur[src] gather (400KB, L2-resident), shuffle reduce, fused
//             bias/surv/clip update. Zero atomics, no k_node pass.
// cur ping-pongs between ws buffer and d_out (last step reads ws, writes clip).

__global__ void k_detect(const unsigned long long* ei, int* flag) {
    if (blockIdx.x == 0 && threadIdx.x == 0) {
        // int64 indices (<2^17) have zero high words; int32 data read as u64
        // carries the next random index in the high word (all-64-zero ~ never).
        int is64 = 1;
        for (int k = 0; k < 64; ++k)
            if ((ei[k] >> 32) != 0ULL) { is64 = 0; break; }
        *flag = is64;
    }
}

__global__ void k_scales(const float* __restrict__ time_decay,
                         const float* __restrict__ edge_weight,
                         float* __restrict__ step_scale, int num_steps) {
    int i = threadIdx.x;
    if (i < num_steps) {
        float td = time_decay[i];
        step_scale[i] = edge_weight[i] * expf(-td * td);
    }
}

// cur0 = x, surv = 1-x, counters = 0.
__global__ void k_init(const float* __restrict__ x, float* __restrict__ cur0,
                       float* __restrict__ surv, unsigned int* __restrict__ cnt, int n) {
    int i = blockIdx.x * blockDim.x + threadIdx.x;
    if (i < n) {
        float v = x[i];
        cur0[i]  = v;
        surv[i]  = 1.0f - v;
        cnt[i]   = 0u;
    }
}

// Count in-degree; optionally record each edge's rank within its dst bucket.
template <int STORE_RANK>
__global__ void k_rank(const void* __restrict__ ei_raw, const int* __restrict__ flag,
                       unsigned int* __restrict__ cnt, unsigned int* __restrict__ rank,
                       int num_edges) {
    const int is64 = *flag;
    const int stride = gridDim.x * blockDim.x;
    if (is64) {
        const long long* d = (const long long*)ei_raw + num_edges;
        for (int e = blockIdx.x * blockDim.x + threadIdx.x; e < num_edges; e += stride) {
            unsigned int r = atomicAdd(&cnt[(int)d[e]], 1u);
            if (STORE_RANK) rank[e] = r;
        }
    } else {
        const int* d = (const int*)ei_raw + num_edges;
        for (int e = blockIdx.x * blockDim.x + threadIdx.x; e < num_edges; e += stride) {
            unsigned int r = atomicAdd(&cnt[d[e]], 1u);
            if (STORE_RANK) rank[e] = r;
        }
    }
}

// Single-block in-place EXCLUSIVE scan over n u32 (chunks of 1024, Hillis-Steele).
__global__ void k_scan(unsigned int* __restrict__ arr, int n) {
    __shared__ unsigned int lds[1024];
    __shared__ unsigned int carry_s;
    const int t = threadIdx.x;
    if (t == 0) carry_s = 0u;
    __syncthreads();
    for (int base = 0; base < n; base += 1024) {
        int i = base + t;
        unsigned int v = (i < n) ? arr[i] : 0u;
        lds[t] = v;
        __syncthreads();
        for (int off = 1; off < 1024; off <<= 1) {
            unsigned int add = (t >= off) ? lds[t - off] : 0u;
            __syncthreads();
            lds[t] += add;
            __syncthreads();
        }
        unsigned int excl = lds[t] - v + carry_s;
        if (i < n) arr[i] = excl;
        __syncthreads();
        if (t == 0) carry_s += lds[1023];
        __syncthreads();
    }
}

// FULL: pos = base[dst] + rank[e]; base (exclusive scan) is left untouched.
__global__ void k_scatter_full(const void* __restrict__ ei_raw, const int* __restrict__ flag,
                               const float* __restrict__ probs,
                               const unsigned int* __restrict__ base,
                               const unsigned int* __restrict__ rank,
                               float2* __restrict__ csr, int num_edges) {
    const int is64 = *flag;
    const int stride = gridDim.x * blockDim.x;
    for (int e = blockIdx.x * blockDim.x + threadIdx.x; e < num_edges; e += stride) {
        int src, dst;
        if (is64) {
            const long long* s = (const long long*)ei_raw;
            src = (int)s[e]; dst = (int)s[e + num_edges];
        } else {
            const int* s = (const int*)ei_raw;
            src = s[e]; dst = s[e + num_edges];
        }
        unsigned int pos = base[dst] + rank[e];
        csr[pos] = make_float2(__uint_as_float((unsigned int)src), probs[e]);
    }
}

// LEAN: cursor atomics (arr seeded with exclusive scan -> ends as inclusive scan).
__global__ void k_scatter_lean(const void* __restrict__ ei_raw, const int* __restrict__ flag,
                               const float* __restrict__ probs,
                               unsigned int* __restrict__ cursor,
                               float2* __restrict__ csr, int num_edges) {
    const int is64 = *flag;
    const int stride = gridDim.x * blockDim.x;
    for (int e = blockIdx.x * blockDim.x + threadIdx.x; e < num_edges; e += stride) {
        int src, dst;
        if (is64) {
            const long long* s = (const long long*)ei_raw;
            src = (int)s[e]; dst = (int)s[e + num_edges];
        } else {
            const int* s = (const int*)ei_raw;
            src = s[e]; dst = s[e + num_edges];
        }
        unsigned int pos = atomicAdd(&cursor[dst], 1u);
        csr[pos] = make_float2(__uint_as_float((unsigned int)src), probs[e]);
    }
}

// One wave per node: coalesced CSR segment read + cur gather + shuffle reduce,
// fused node update. INCL=1: arr is inclusive scan; INCL=0: exclusive.
// wflags: 1 = write cur_out, 2 = write clipped output.
template <int INCL>
__global__ void k_step(const float2* __restrict__ csr, const unsigned int* __restrict__ arr,
                       const float* __restrict__ cur_in, float* __restrict__ cur_out,
                       float* __restrict__ surv, const float* __restrict__ step_scale,
                       const float* __restrict__ bias_p, float* __restrict__ out,
                       int step, int n, int num_edges, int wflags) {
    int gid  = blockIdx.x * blockDim.x + threadIdx.x;
    int node = gid >> 6;
    int lane = gid & 63;
    if (node >= n) return;
    unsigned int beg, end;
    if (INCL) { beg = node ? arr[node - 1] : 0u; end = arr[node]; }
    else      { beg = arr[node]; end = (node + 1 < n) ? arr[node + 1] : (unsigned int)num_edges; }
    float sum = 0.0f;
    for (unsigned int j = beg + lane; j < end; j += 64) {
        float2 sp = csr[j];
        sum += cur_in[__float_as_uint(sp.x)] * sp.y;
    }
#pragma unroll
    for (int off = 32; off; off >>= 1) sum += __shfl_xor(sum, off, 64);
    if (lane == 0) {
        float c = sum * step_scale[step] + bias_p[0];
        if (wflags & 1) cur_out[node] = c;
        float s = surv[node] * (1.0f - c);
        surv[node] = s;
        if (wflags & 2) out[node] = fminf(fmaxf(1.0f - s, 0.0f), 1.0f);
    }
}

// --- minimal fallback (ws too small for CSR; not expected) ---
__global__ void k_edge_raw(const void* __restrict__ ei_raw, const int* __restrict__ flag,
                           const float* __restrict__ probs, const float* __restrict__ cur,
                           float* __restrict__ acc, const float* __restrict__ step_scale,
                           int step, int num_edges) {
    const float scale = step_scale[step];
    const int is64 = *flag;
    const int stride = gridDim.x * blockDim.x;
    for (int e = blockIdx.x * blockDim.x + threadIdx.x; e < num_edges; e += stride) {
        int src, dst;
        if (is64) {
            const long long* s = (const long long*)ei_raw;
            src = (int)s[e]; dst = (int)s[e + num_edges];
        } else {
            const int* s = (const int*)ei_raw;
            src = s[e]; dst = s[e + num_edges];
        }
        atomicAdd(&acc[dst], cur[src] * (probs[e] * scale));
    }
}

__global__ void k_node(float* __restrict__ cur, float* __restrict__ acc,
                       float* __restrict__ surv, const float* __restrict__ bias_p,
                       float* __restrict__ out, int n, int write_out) {
    int i = blockIdx.x * blockDim.x + threadIdx.x;
    if (i < n) {
        float c = acc[i] + bias_p[0];
        acc[i] = 0.0f;
        cur[i] = c;
        float s = surv[i] * (1.0f - c);
        surv[i] = s;
        if (write_out) out[i] = fminf(fmaxf(1.0f - s, 0.0f), 1.0f);
    }
}

static inline size_t align8(size_t x) { return (x + 7) & ~(size_t)7; }

extern "C" void kernel_launch(void* const* d_in, const int* in_sizes, int n_in,
                              void* d_out, int out_size, void* d_ws, size_t ws_size,
                              hipStream_t stream) {
    const float* x           = (const float*)d_in[0];
    const void*  ei          = d_in[1];
    const float* probs       = (const float*)d_in[2];
    const float* time_decay  = (const float*)d_in[3];
    const float* node_bias   = (const float*)d_in[4];
    const float* edge_weight = (const float*)d_in[5];
    float* outf = (float*)d_out;

    const int n = in_sizes[0];
    const int E = in_sizes[2];
    const int S = in_sizes[3];

    char* ws = (char*)d_ws;
    const size_t nb = (size_t)n * 4;

    // Layouts. FULL: bufA | surv | arr | rank(4E) | csr(8E) | flag/scales(64)
    //          LEAN: bufA | surv | arr |           csr(8E)  | flag/scales(64)
    const size_t off_bufA = 0, off_surv = nb, off_arr = 2 * nb;
    const size_t off_rank     = align8(3 * nb);
    const size_t off_csr_full = align8(off_rank + 4 * (size_t)E);
    const size_t full_req     = off_csr_full + 8 * (size_t)E + 64;
    const size_t off_csr_lean = align8(3 * nb);
    const size_t lean_req     = off_csr_lean + 8 * (size_t)E + 64;

    const int nthreads  = 256;
    const int node_grid = (n + nthreads - 1) / nthreads;
    const int edge_grid = 2048;
    const int step_grid = (int)(((size_t)n * 64 + nthreads - 1) / nthreads);

    float*        bufA = (float*)(ws + off_bufA);
    float*        surv = (float*)(ws + off_surv);
    unsigned int* arr  = (unsigned int*)(ws + off_arr);

    int tier = (ws_size >= full_req) ? 2 : (ws_size >= lean_req) ? 1 : 0;
    size_t tail = (tier == 2) ? (full_req - 64) : (tier == 1) ? (lean_req - 64)
                               : align8(3 * nb);
    int*   flag       = (int*)(ws + tail);
    float* step_scale = (float*)(ws + tail + 8);

    k_detect<<<1, 64, 0, stream>>>((const unsigned long long*)ei, flag);
    k_scales<<<1, 64, 0, stream>>>(time_decay, edge_weight, step_scale, S);

    if (tier == 0) {
        // cur = bufA, acc = arr (zeroed by k_init; float 0.0 == bits 0).
        k_init<<<node_grid, nthreads, 0, stream>>>(x, bufA, surv, arr, n);
        for (int s = 0; s < S; ++s) {
            k_edge_raw<<<edge_grid, nthreads, 0, stream>>>(ei, flag, probs, bufA, (float*)arr,
                                                           step_scale, s, E);
            k_node<<<node_grid, nthreads, 0, stream>>>(bufA, (float*)arr, surv, node_bias,
                                                       outf, n, s == S - 1 ? 1 : 0);
        }
        return;
    }

    float2* csr = (float2*)(ws + (tier == 2 ? off_csr_full : off_csr_lean));
    unsigned int* rank = (unsigned int*)(ws + off_rank);

    // cur ping-pong between bufA and d_out; last step must read a ws buffer.
    float* b0 = (S % 2 == 0) ? outf : bufA;   // cur_in for even s
    float* b1 = (S % 2 == 0) ? bufA : outf;   // cur_in for odd s

    k_init<<<node_grid, nthreads, 0, stream>>>(x, b0, surv, arr, n);

    if (tier == 2) {
        k_rank<1><<<edge_grid, nthreads, 0, stream>>>(ei, flag, arr, rank, E);
        k_scan<<<1, 1024, 0, stream>>>(arr, n);
        k_scatter_full<<<edge_grid, nthreads, 0, stream>>>(ei, flag, probs, arr, rank, csr, E);
        for (int s = 0; s < S; ++s) {
            float* ci = (s % 2 == 0) ? b0 : b1;
            float* co = (s % 2 == 0) ? b1 : b0;
            k_step<0><<<step_grid, nthreads, 0, stream>>>(csr, arr, ci, co, surv, step_scale,
                                                          node_bias, outf, s, n, E,
                                                          s == S - 1 ? 2 : 1);
        }
    } else {
        k_rank<0><<<edge_grid, nthreads, 0, stream>>>(ei, flag, arr, nullptr, E);
        k_scan<<<1, 1024, 0, stream>>>(arr, n);
        k_scatter_lean<<<edge_grid, nthreads, 0, stream>>>(ei, flag, probs, arr, csr, E);
        for (int s = 0; s < S; ++s) {
            float* ci = (s % 2 == 0) ? b0 : b1;
            float* co = (s % 2 == 0) ? b1 : b0;
            k_step<1><<<step_grid, nthreads, 0, stream>>>(csr, arr, ci, co, surv, step_scale,
                                                          node_bias, outf, s, n, E,
                                                          s == S - 1 ? 2 : 1);
        }
    }
}

// Round 4
// 745.364 us; speedup vs baseline: 4.6081x; 1.5273x over previous
//
#include <hip/hip_runtime.h>

// Graph-diffusion, 10 steps of edge-scatter + node update.
//
// R3 post-mortem: CSR-build atomic pass (k_rank, 290us, 224MB memory-side
// writes at ~22G atomics/s) dominates since the build is re-done every call
// (ws re-poisoned). R4: atomic-free build via two-pass LDS-histogram
// partition by coarse bucket (dst>>5, 32 nodes/bucket):
//   k_hist  : per-block LDS histogram -> per-(bin,block) counts (no atomics)
//   scan    : parallel 3-kernel exclusive scan (bin-major) -> write cursors
//   k_part  : re-read edges, LDS cursor atomics place each edge in its
//             exclusive slot; payload = (src | dst_low<<17, prob) 8B
//   k_step  : one block per bucket streams its contiguous segment, LDS
//             accumulate (4-way replicated), fused bias/surv/clip update.
// Zero global atomics anywhere.

#define PART_BLOCKS 256
#define TPB 256

__global__ void k_detect(const unsigned long long* ei, int* flag) {
    if (blockIdx.x == 0 && threadIdx.x == 0) {
        // int64 indices (<2^17) have zero high words; int32 data read as u64
        // carries a random index in the high word (all-64-zero ~ never).
        int is64 = 1;
        for (int k = 0; k < 64; ++k)
            if ((ei[k] >> 32) != 0ULL) { is64 = 0; break; }
        *flag = is64;
    }
}

__global__ void k_scales(const float* __restrict__ time_decay,
                         const float* __restrict__ edge_weight,
                         float* __restrict__ step_scale, int num_steps) {
    int i = threadIdx.x;
    if (i < num_steps) {
        float td = time_decay[i];
        step_scale[i] = edge_weight[i] * expf(-td * td);
    }
}

__global__ void k_init(const float* __restrict__ x, float* __restrict__ cur0,
                       float* __restrict__ surv, int n) {
    int i = blockIdx.x * blockDim.x + threadIdx.x;
    if (i < n) {
        float v = x[i];
        cur0[i] = v;
        surv[i] = 1.0f - v;
    }
}

// Per-block LDS histogram of dst>>5 over this block's edge chunk.
__global__ void k_hist(const void* __restrict__ ei_raw, const int* __restrict__ flag,
                       unsigned int* __restrict__ ph, int E, int nbins, int chunk) {
    extern __shared__ unsigned int h[];
    const int b = blockIdx.x, t = threadIdx.x;
    for (int i = t; i < nbins; i += TPB) h[i] = 0u;
    __syncthreads();
    const int beg = b * chunk;
    const int end = min(E, beg + chunk);
    if (*flag) {
        const long long* dd = (const long long*)ei_raw + E;
        for (int e = beg + t; e < end; e += TPB)
            atomicAdd(&h[((int)dd[e]) >> 5], 1u);
    } else {
        const int* dd = (const int*)ei_raw + E;
        for (int e = beg + t; e < end; e += TPB)
            atomicAdd(&h[dd[e] >> 5], 1u);
    }
    __syncthreads();
    for (int i = t; i < nbins; i += TPB)
        ph[(size_t)i * PART_BLOCKS + b] = h[i];     // bin-major
}

// 3-kernel device exclusive scan over ntotal (= nbins*PART_BLOCKS, mult of 1024).
__global__ void k_scan1(unsigned int* __restrict__ arr, unsigned int* __restrict__ partials,
                        int ntotal) {
    __shared__ unsigned int lds[1024];
    const int t = threadIdx.x;
    int i = blockIdx.x * 1024 + t;
    unsigned int v = (i < ntotal) ? arr[i] : 0u;
    lds[t] = v;
    __syncthreads();
    for (int off = 1; off < 1024; off <<= 1) {
        unsigned int a = (t >= off) ? lds[t - off] : 0u;
        __syncthreads();
        lds[t] += a;
        __syncthreads();
    }
    if (i < ntotal) arr[i] = lds[t] - v;
    if (t == 0) partials[blockIdx.x] = lds[1023];
}

__global__ void k_scan2(unsigned int* __restrict__ partials, int nb) {
    __shared__ unsigned int lds[1024];
    const int t = threadIdx.x;
    unsigned int v = (t < nb) ? partials[t] : 0u;
    lds[t] = v;
    __syncthreads();
    for (int off = 1; off < 1024; off <<= 1) {
        unsigned int a = (t >= off) ? lds[t - off] : 0u;
        __syncthreads();
        lds[t] += a;
        __syncthreads();
    }
    if (t < nb) partials[t] = lds[t] - v;
}

__global__ void k_scan3(unsigned int* __restrict__ arr, const unsigned int* __restrict__ partials,
                        int ntotal) {
    int i = blockIdx.x * 1024 + threadIdx.x;
    if (i < ntotal) arr[i] += partials[blockIdx.x];
}

// Partition edges into coarse buckets; exclusive slots via LDS cursors.
__global__ void k_part(const void* __restrict__ ei_raw, const int* __restrict__ flag,
                       const float* __restrict__ probs, const unsigned int* __restrict__ ph,
                       float2* __restrict__ sorted, int E, int nbins, int chunk) {
    extern __shared__ unsigned int cur[];
    const int b = blockIdx.x, t = threadIdx.x;
    for (int i = t; i < nbins; i += TPB)
        cur[i] = ph[(size_t)i * PART_BLOCKS + b];
    __syncthreads();
    const int beg = b * chunk;
    const int end = min(E, beg + chunk);
    const int is64 = *flag;
    for (int e = beg + t; e < end; e += TPB) {
        int src, dst;
        if (is64) {
            const long long* s = (const long long*)ei_raw;
            src = (int)s[e]; dst = (int)s[e + E];
        } else {
            const int* s = (const int*)ei_raw;
            src = s[e]; dst = s[e + E];
        }
        unsigned int pos = atomicAdd(&cur[dst >> 5], 1u);
        sorted[pos] = make_float2(
            __uint_as_float((unsigned int)src | ((unsigned int)(dst & 31) << 17)),
            probs[e]);
    }
}

// One block per bucket: stream contiguous segment, LDS-accumulate 32 nodes
// (4-way replicated, +1 pad), fused node update. Zero atomics to global.
__global__ void k_step(const float2* __restrict__ sorted, const unsigned int* __restrict__ ph,
                       const float* __restrict__ cur_in, float* __restrict__ cur_out,
                       float* __restrict__ surv, const float* __restrict__ step_scale,
                       const float* __restrict__ bias_p, float* __restrict__ out,
                       int step, int n, int E, int nbins, int last) {
    __shared__ float acc[4][33];
    const int bin = blockIdx.x, t = threadIdx.x;
    if (t < 132) ((float*)acc)[t] = 0.0f;
    __syncthreads();
    unsigned int s0 = ph[(size_t)bin * PART_BLOCKS];
    unsigned int s1 = (bin + 1 < nbins) ? ph[(size_t)(bin + 1) * PART_BLOCKS]
                                        : (unsigned int)E;
    for (unsigned int j = s0 + t; j < s1; j += TPB) {
        float2 kp = sorted[j];
        unsigned int k = __float_as_uint(kp.x);
        float m = cur_in[k & 0x1FFFFu] * kp.y;
        atomicAdd(&acc[t & 3][k >> 17], m);
    }
    __syncthreads();
    if (t < 32) {
        int node = (bin << 5) + t;
        if (node < n) {
            float c = (acc[0][t] + acc[1][t] + acc[2][t] + acc[3][t]) * step_scale[step]
                      + bias_p[0];
            if (!last) cur_out[node] = c;
            float sv = surv[node] * (1.0f - c);
            surv[node] = sv;
            if (last) out[node] = fminf(fmaxf(1.0f - sv, 0.0f), 1.0f);
        }
    }
}

// --- minimal fallback (ws too small; not expected) ---
__global__ void k_init0(const float* __restrict__ x, float* __restrict__ cur,
                        float* __restrict__ surv, float* __restrict__ acc, int n) {
    int i = blockIdx.x * blockDim.x + threadIdx.x;
    if (i < n) {
        float v = x[i];
        cur[i] = v; surv[i] = 1.0f - v; acc[i] = 0.0f;
    }
}

__global__ void k_edge_raw(const void* __restrict__ ei_raw, const int* __restrict__ flag,
                           const float* __restrict__ probs, const float* __restrict__ cur,
                           float* __restrict__ acc, const float* __restrict__ step_scale,
                           int step, int num_edges) {
    const float scale = step_scale[step];
    const int is64 = *flag;
    const int stride = gridDim.x * blockDim.x;
    for (int e = blockIdx.x * blockDim.x + threadIdx.x; e < num_edges; e += stride) {
        int src, dst;
        if (is64) {
            const long long* s = (const long long*)ei_raw;
            src = (int)s[e]; dst = (int)s[e + num_edges];
        } else {
            const int* s = (const int*)ei_raw;
            src = s[e]; dst = s[e + num_edges];
        }
        atomicAdd(&acc[dst], cur[src] * (probs[e] * scale));
    }
}

__global__ void k_node(float* __restrict__ cur, float* __restrict__ acc,
                       float* __restrict__ surv, const float* __restrict__ bias_p,
                       float* __restrict__ out, int n, int write_out) {
    int i = blockIdx.x * blockDim.x + threadIdx.x;
    if (i < n) {
        float c = acc[i] + bias_p[0];
        acc[i] = 0.0f;
        cur[i] = c;
        float s = surv[i] * (1.0f - c);
        surv[i] = s;
        if (write_out) out[i] = fminf(fmaxf(1.0f - s, 0.0f), 1.0f);
    }
}

static inline size_t al256(size_t x) { return (x + 255) & ~(size_t)255; }

extern "C" void kernel_launch(void* const* d_in, const int* in_sizes, int n_in,
                              void* d_out, int out_size, void* d_ws, size_t ws_size,
                              hipStream_t stream) {
    const float* x           = (const float*)d_in[0];
    const void*  ei          = d_in[1];
    const float* probs       = (const float*)d_in[2];
    const float* time_decay  = (const float*)d_in[3];
    const float* node_bias   = (const float*)d_in[4];
    const float* edge_weight = (const float*)d_in[5];
    float* outf = (float*)d_out;

    const int n = in_sizes[0];
    const int E = in_sizes[2];
    const int S = in_sizes[3];

    char* ws = (char*)d_ws;
    int*   flag       = (int*)ws;          // 4B at offset 0
    float* step_scale = (float*)(ws + 64); // S floats

    const size_t nbA = al256((size_t)n * 4);
    const int nbins  = (((n + 31) >> 5) + 3) & ~3;          // mult of 4
    const int ntotal = nbins * PART_BLOCKS;                  // mult of 1024
    const int scanB  = ntotal / 1024;
    const int chunk  = (E + PART_BLOCKS - 1) / PART_BLOCKS;

    const size_t off_buf    = 256;
    const size_t off_surv   = off_buf + nbA;
    const size_t off_ph     = off_surv + nbA;
    const size_t ph_bytes   = (size_t)ntotal * 4;
    const size_t off_part   = al256(off_ph + ph_bytes);
    const size_t off_sorted = al256(off_part + (size_t)scanB * 4);
    const size_t req        = off_sorted + (size_t)E * 8;

    const int nthreads  = 256;
    const int node_grid = (n + nthreads - 1) / nthreads;

    const bool ok = (n <= (1 << 17)) && (scanB >= 1) && (scanB <= 1024) &&
                    (ws_size >= req) && (E > 0);

    k_detect<<<1, 64, 0, stream>>>((const unsigned long long*)ei, flag);
    k_scales<<<1, 64, 0, stream>>>(time_decay, edge_weight, step_scale, S);

    if (!ok) {
        // Raw-atomic fallback: cur | surv | acc (3*nbA).
        float* cur  = (float*)(ws + off_buf);
        float* surv = (float*)(ws + off_surv);
        float* acc  = (float*)(ws + off_surv + nbA);
        k_init0<<<node_grid, nthreads, 0, stream>>>(x, cur, surv, acc, n);
        for (int s = 0; s < S; ++s) {
            k_edge_raw<<<2048, nthreads, 0, stream>>>(ei, flag, probs, cur, acc,
                                                      step_scale, s, E);
            k_node<<<node_grid, nthreads, 0, stream>>>(cur, acc, surv, node_bias,
                                                       outf, n, s == S - 1 ? 1 : 0);
        }
        return;
    }

    float*        bufA   = (float*)(ws + off_buf);
    float*        surv   = (float*)(ws + off_surv);
    unsigned int* ph     = (unsigned int*)(ws + off_ph);
    unsigned int* parts  = (unsigned int*)(ws + off_part);
    float2*       sorted = (float2*)(ws + off_sorted);

    // cur ping-pong: last step (s=S-1) must READ a ws buffer.
    float* b0 = (S % 2 == 0) ? outf : bufA;   // cur_in for even s
    float* b1 = (S % 2 == 0) ? bufA : outf;   // cur_in for odd s

    k_init<<<node_grid, nthreads, 0, stream>>>(x, b0, surv, n);

    k_hist<<<PART_BLOCKS, TPB, (size_t)nbins * 4, stream>>>(ei, flag, ph, E, nbins, chunk);
    k_scan1<<<scanB, 1024, 0, stream>>>(ph, parts, ntotal);
    k_scan2<<<1, 1024, 0, stream>>>(parts, scanB);
    k_scan3<<<scanB, 1024, 0, stream>>>(ph, parts, ntotal);
    k_part<<<PART_BLOCKS, TPB, (size_t)nbins * 4, stream>>>(ei, flag, probs, ph, sorted,
                                                            E, nbins, chunk);

    for (int s = 0; s < S; ++s) {
        float* ci = (s % 2 == 0) ? b0 : b1;
        float* co = (s % 2 == 0) ? b1 : b0;
        k_step<<<nbins, TPB, 0, stream>>>(sorted, ph, ci, co, surv, step_scale,
                                          node_bias, outf, s, n, E, nbins,
                                          s == S - 1 ? 1 : 0);
    }
}

// Round 8
// 686.199 us; speedup vs baseline: 5.0054x; 1.0862x over previous
//
#include <hip/hip_runtime.h>
#include <math.h>

// Graph-diffusion, 10 steps of edge-scatter + node update.
//
// R4 post-mortem: k_part = 213us, WRITE_SIZE 182MB for a 51MB payload (8B
// scattered stores -> ~3.5x line-granular write amp) at 10% occupancy.
// R5..R7: single-pass LDS-staged bucketing into coarse buckets (2048 nodes):
//   k_bucket: per-block LDS staging (64 bins x 64 slots), per-round wave
//             prefix + BATCHED global cursor reservation (~49 atomics per
//             2048 edges, ~150K total vs 6.4M), coalesced flush runs (~42
//             edges) into fixed-capacity bucket regions (slack >= 6 sigma,
//             guarded per-edge overflow path).
//   k_step  : (bin,split) per block; LDS acc 2048 nodes (2-way replicated);
//             partial written NON-atomically to an exclusive global slot.
//   k_reduce: sum partials + fused scale/bias/surv/clip.
// SPLITS and capacity slack chosen at runtime to fit ws_size (fast path
// engages for ws >= ~53MB; R4 proved ws >= ~55MB).

#define MAXBINS     64
#define BIN_SHIFT   11
#define BIN_SIZE    2048      // 1 << BIN_SHIFT
#define STAGE_CAP   64        // LDS staging slots per bin
#define BUCKET_GRID 768
#define BUCKET_TPB  256
#define BUCKET_K    8         // edges per thread per round
#define STEP_TPB    256

__global__ void k_detect(const unsigned long long* ei, int* flag) {
    if (blockIdx.x == 0 && threadIdx.x == 0) {
        // int64 indices (<2^17) have zero high words; int32 data read as u64
        // carries a random index in the high word (all-64-zero ~ never).
        int is64 = 1;
        for (int k = 0; k < 64; ++k)
            if ((ei[k] >> 32) != 0ULL) { is64 = 0; break; }
        *flag = is64;
    }
}

// scales + zero the global bucket cursors.
__global__ void k_scales(const float* __restrict__ time_decay,
                         const float* __restrict__ edge_weight,
                         float* __restrict__ step_scale, int num_steps,
                         unsigned int* __restrict__ gcur) {
    int i = threadIdx.x;
    if (i < num_steps) {
        float td = time_decay[i];
        step_scale[i] = edge_weight[i] * expf(-td * td);
    }
    if (i < MAXBINS) gcur[i] = 0u;
}

__global__ void k_init(const float* __restrict__ x, float* __restrict__ cur0,
                       float* __restrict__ surv, int n) {
    int i = blockIdx.x * blockDim.x + threadIdx.x;
    if (i < n) {
        float v = x[i];
        cur0[i] = v;
        surv[i] = 1.0f - v;
    }
}

// Single-pass bucketing with LDS staging and batched cursor reservation.
__global__ void k_bucket(const void* __restrict__ ei_raw, const int* __restrict__ flag,
                         const float* __restrict__ probs, unsigned int* __restrict__ gcur,
                         float2* __restrict__ sorted, unsigned int capr,
                         int E, int nbins) {
    __shared__ float2 buf[MAXBINS][STAGE_CAP];
    __shared__ unsigned int cnt[MAXBINS];
    __shared__ unsigned int gbase[MAXBINS];
    __shared__ unsigned int pref[MAXBINS + 1];
    const int t = threadIdx.x;
    const int is64 = *flag;
    const int chunk = (E + gridDim.x - 1) / gridDim.x;
    const int beg = blockIdx.x * chunk;
    const int end = min(E, beg + chunk);
    for (int i = t; i < nbins; i += BUCKET_TPB) cnt[i] = 0u;
    __syncthreads();
    const int ROUND = BUCKET_TPB * BUCKET_K;
    for (int rbeg = beg; rbeg < end; rbeg += ROUND) {
        // ---- insert phase ----
        for (int k = 0; k < BUCKET_K; ++k) {
            int e = rbeg + k * BUCKET_TPB + t;
            if (e < end) {
                int src, dst;
                if (is64) {
                    const long long* s = (const long long*)ei_raw;
                    src = (int)s[e]; dst = (int)s[e + E];
                } else {
                    const int* s = (const int*)ei_raw;
                    src = s[e]; dst = s[e + E];
                }
                float pr = probs[e];
                int bin = dst >> BIN_SHIFT;
                unsigned int payload = (unsigned int)src |
                                       ((unsigned int)(dst & (BIN_SIZE - 1)) << 17);
                unsigned int pos = atomicAdd(&cnt[bin], 1u);
                if (pos < STAGE_CAP) {
                    buf[bin][pos] = make_float2(__uint_as_float(payload), pr);
                } else {
                    // rare overflow: direct per-edge reservation (guarded)
                    unsigned int gp = atomicAdd(&gcur[bin], 1u);
                    if (gp < capr)
                        sorted[(size_t)bin * capr + gp] =
                            make_float2(__uint_as_float(payload), pr);
                }
            }
        }
        __syncthreads();
        // ---- prefix over staged counts + batched reservation (wave 0) ----
        if (t < 64) {
            unsigned int c = (t < nbins) ? min(cnt[t], (unsigned int)STAGE_CAP) : 0u;
            unsigned int inc = c;
            for (int off = 1; off < 64; off <<= 1) {
                unsigned int u = __shfl_up(inc, off, 64);
                if (t >= off) inc += u;
            }
            pref[t + 1] = inc;
            if (t == 0) pref[0] = 0u;
            if (t < nbins && c > 0u) gbase[t] = atomicAdd(&gcur[t], c);
        }
        __syncthreads();
        // ---- coalesced flush ----
        int total = (int)pref[nbins];
        for (int i = t; i < total; i += BUCKET_TPB) {
            int lo = 0, hi = nbins - 1;
            while (lo < hi) {                       // find bin: pref[b] <= i < pref[b+1]
                int mid = (lo + hi + 1) >> 1;
                if ((int)pref[mid] <= i) lo = mid; else hi = mid - 1;
            }
            int idx = i - (int)pref[lo];
            unsigned int gp = gbase[lo] + (unsigned int)idx;
            if (gp < capr)
                sorted[(size_t)lo * capr + gp] = buf[lo][idx];
        }
        __syncthreads();
        for (int i = t; i < nbins; i += BUCKET_TPB) cnt[i] = 0u;
        __syncthreads();
    }
}

// (bin, split) per block: LDS-accumulate 2048 nodes, write exclusive partial.
__global__ void k_step(const float2* __restrict__ sorted, const unsigned int* __restrict__ gcur,
                       const float* __restrict__ cur_in, float* __restrict__ part,
                       unsigned int capr, int pstride, int nbins, int splits) {
    __shared__ float acc[2][BIN_SIZE];
    const int bin = blockIdx.x / splits;
    const int sp  = blockIdx.x - bin * splits;
    const int t = threadIdx.x;
    float* accf = (float*)acc;
    for (int i = t; i < 2 * BIN_SIZE; i += STEP_TPB) accf[i] = 0.0f;
    __syncthreads();
    unsigned int cntv = min(gcur[bin], capr);
    unsigned int sub = (cntv + (unsigned int)splits - 1) / (unsigned int)splits;
    unsigned int s0 = min(cntv, (unsigned int)sp * sub);
    unsigned int s1 = min(cntv, s0 + sub);
    const float2* base = sorted + (size_t)bin * capr;
    for (unsigned int j = s0 + t; j < s1; j += STEP_TPB) {
        float2 kp = base[j];
        unsigned int v = __float_as_uint(kp.x);
        float m = cur_in[v & 0x1FFFFu] * kp.y;
        atomicAdd(&acc[t & 1][v >> 17], m);
    }
    __syncthreads();
    float* dst = part + (size_t)sp * pstride + (size_t)bin * BIN_SIZE;
    for (int i = t; i < BIN_SIZE; i += STEP_TPB)
        dst[i] = acc[0][i] + acc[1][i];             // unconditional (no poison left)
}

// Sum partials + fused scale/bias/surv/clip.
__global__ void k_reduce(const float* __restrict__ part, int pstride, int splits,
                         float* __restrict__ cur_out, float* __restrict__ surv,
                         const float* __restrict__ step_scale, const float* __restrict__ bias_p,
                         float* __restrict__ out, int step, int n, int last) {
    int i = blockIdx.x * blockDim.x + threadIdx.x;
    if (i >= n) return;
    float c = 0.0f;
    for (int s = 0; s < splits; ++s) c += part[(size_t)s * pstride + i];
    c = c * step_scale[step] + bias_p[0];
    if (!last) cur_out[i] = c;
    float sv = surv[i] * (1.0f - c);
    surv[i] = sv;
    if (last) out[i] = fminf(fmaxf(1.0f - sv, 0.0f), 1.0f);
}

// --- minimal fallback (ws too small / n too big; not expected) ---
__global__ void k_init0(const float* __restrict__ x, float* __restrict__ cur,
                        float* __restrict__ surv, float* __restrict__ acc, int n) {
    int i = blockIdx.x * blockDim.x + threadIdx.x;
    if (i < n) {
        float v = x[i];
        cur[i] = v; surv[i] = 1.0f - v; acc[i] = 0.0f;
    }
}

__global__ void k_edge_raw(const void* __restrict__ ei_raw, const int* __restrict__ flag,
                           const float* __restrict__ probs, const float* __restrict__ cur,
                           float* __restrict__ acc, const float* __restrict__ step_scale,
                           int step, int num_edges) {
    const float scale = step_scale[step];
    const int is64 = *flag;
    const int stride = gridDim.x * blockDim.x;
    for (int e = blockIdx.x * blockDim.x + threadIdx.x; e < num_edges; e += stride) {
        int src, dst;
        if (is64) {
            const long long* s = (const long long*)ei_raw;
            src = (int)s[e]; dst = (int)s[e + num_edges];
        } else {
            const int* s = (const int*)ei_raw;
            src = s[e]; dst = s[e + num_edges];
        }
        atomicAdd(&acc[dst], cur[src] * (probs[e] * scale));
    }
}

__global__ void k_node(float* __restrict__ cur, float* __restrict__ acc,
                       float* __restrict__ surv, const float* __restrict__ bias_p,
                       float* __restrict__ out, int n, int write_out) {
    int i = blockIdx.x * blockDim.x + threadIdx.x;
    if (i < n) {
        float c = acc[i] + bias_p[0];
        acc[i] = 0.0f;
        cur[i] = c;
        float s = surv[i] * (1.0f - c);
        surv[i] = s;
        if (write_out) out[i] = fminf(fmaxf(1.0f - s, 0.0f), 1.0f);
    }
}

static inline size_t al256(size_t x) { return (x + 255) & ~(size_t)255; }

extern "C" void kernel_launch(void* const* d_in, const int* in_sizes, int n_in,
                              void* d_out, int out_size, void* d_ws, size_t ws_size,
                              hipStream_t stream) {
    const float* x           = (const float*)d_in[0];
    const void*  ei          = d_in[1];
    const float* probs       = (const float*)d_in[2];
    const float* time_decay  = (const float*)d_in[3];
    const float* node_bias   = (const float*)d_in[4];
    const float* edge_weight = (const float*)d_in[5];
    float* outf = (float*)d_out;

    const int n = in_sizes[0];
    const int E = in_sizes[2];
    const int S = in_sizes[3];

    char* ws = (char*)d_ws;
    int*          flag       = (int*)ws;                    // 4B @ 0
    float*        step_scale = (float*)(ws + 64);           // S floats
    unsigned int* gcur       = (unsigned int*)(ws + 256);   // MAXBINS u32

    const int nbins   = (n + BIN_SIZE - 1) >> BIN_SHIFT;
    const int pstride = nbins * BIN_SIZE;

    // Bucket-region capacity: want mean+16sigma, accept down to mean+6sigma.
    const double   meand  = (double)E / (nbins > 0 ? nbins : 1);
    const double   sigma  = sqrt(meand > 1.0 ? meand : 1.0);
    unsigned int   want   = (unsigned int)(meand + 16.0 * sigma + 64.0);
    unsigned int   least  = (unsigned int)(meand + 6.0 * sigma + 64.0);
    want  = (want  + 63u) & ~63u;
    least = (least + 63u) & ~63u;

    const size_t nbA      = al256((size_t)n * 4);
    const size_t off_buf  = 512;
    const size_t off_surv = off_buf + nbA;
    const size_t off_part = al256(off_surv + nbA);

    // Choose largest SPLITS whose layout fits with capr >= least.
    int splits = 0;
    unsigned int capr = 0;
    size_t off_sort = 0;
    const int cand[5] = {16, 12, 8, 6, 4};
    for (int ci = 0; ci < 5; ++ci) {
        int sp = cand[ci];
        size_t part_b = (size_t)sp * pstride * 4;
        size_t osort  = al256(off_part + part_b);
        if (ws_size <= osort) continue;
        size_t availb = ws_size - osort;
        unsigned int acap = (unsigned int)((availb / ((size_t)nbins * 8)) & ~(size_t)63);
        if (acap >= least) {
            splits  = sp;
            capr    = acap < want ? acap : want;
            off_sort = osort;
            break;
        }
    }

    const int nthreads  = 256;
    const int node_grid = (n + nthreads - 1) / nthreads;

    const bool ok = (n <= (1 << 17)) && (nbins >= 1) && (nbins <= MAXBINS) &&
                    (E > 0) && (splits > 0);

    k_detect<<<1, 64, 0, stream>>>((const unsigned long long*)ei, flag);
    k_scales<<<1, 64, 0, stream>>>(time_decay, edge_weight, step_scale, S, gcur);

    if (!ok) {
        // Raw-atomic fallback: cur | surv | acc.
        float* cur  = (float*)(ws + off_buf);
        float* surv = (float*)(ws + off_surv);
        float* acc  = (float*)(ws + off_surv + nbA);
        k_init0<<<node_grid, nthreads, 0, stream>>>(x, cur, surv, acc, n);
        for (int s = 0; s < S; ++s) {
            k_edge_raw<<<2048, nthreads, 0, stream>>>(ei, flag, probs, cur, acc,
                                                      step_scale, s, E);
            k_node<<<node_grid, nthreads, 0, stream>>>(cur, acc, surv, node_bias,
                                                       outf, n, s == S - 1 ? 1 : 0);
        }
        return;
    }

    float*  bufA   = (float*)(ws + off_buf);
    float*  surv   = (float*)(ws + off_surv);
    float*  part   = (float*)(ws + off_part);
    float2* sorted = (float2*)(ws + off_sort);

    // cur ping-pong: last step (s=S-1) must READ a ws buffer.
    float* b0 = (S % 2 == 0) ? outf : bufA;   // cur_in for even s
    float* b1 = (S % 2 == 0) ? bufA : outf;   // cur_in for odd s

    k_init<<<node_grid, nthreads, 0, stream>>>(x, b0, surv, n);

    k_bucket<<<BUCKET_GRID, BUCKET_TPB, 0, stream>>>(ei, flag, probs, gcur, sorted,
                                                     capr, E, nbins);

    const int step_grid = nbins * splits;
    for (int s = 0; s < S; ++s) {
        float* ci = (s % 2 == 0) ? b0 : b1;
        float* co = (s % 2 == 0) ? b1 : b0;
        k_step<<<step_grid, STEP_TPB, 0, stream>>>(sorted, gcur, ci, part,
                                                   capr, pstride, nbins, splits);
        k_reduce<<<node_grid, nthreads, 0, stream>>>(part, pstride, splits, co, surv,
                                                     step_scale, node_bias, outf,
                                                     s, n, s == S - 1 ? 1 : 0);
    }
}

// Round 9
// 682.008 us; speedup vs baseline: 5.0362x; 1.0061x over previous
//
#include <hip/hip_runtime.h>
#include <math.h>

// Graph-diffusion, 10 steps of edge-scatter + node update.
//
// R8 post-mortem: k_bucket 94us (occupancy 27%, 1.8M LDS conflicts from
// binary-search flush + cnt atomics); steps ~58us each (k_step likely at
// splits=4 -> 196 blocks x 4 waves = 1 wave/SIMD, latency-bound gathers).
// R9: (1) k_step TPB=1024 (16 waves/block -> 4 waves/SIMD even at splits=4),
//     4-way replicated LDS acc; (2) k_bucket flush = one bin per wave
//     (cnt<=64=wave width), deleting the prefix scan + binary search;
//     grid 1024 (4 blocks/CU = LDS cap).

#define MAXBINS     64
#define BIN_SHIFT   11
#define BIN_SIZE    2048      // 1 << BIN_SHIFT
#define STAGE_CAP   64        // LDS staging slots per bin (= wave width)
#define BUCKET_GRID 1024
#define BUCKET_TPB  256
#define BUCKET_K    8         // edges per thread per round
#define STEP_TPB    1024

__global__ void k_detect(const unsigned long long* ei, int* flag) {
    if (blockIdx.x == 0 && threadIdx.x == 0) {
        // int64 indices (<2^17) have zero high words; int32 data read as u64
        // carries a random index in the high word (all-64-zero ~ never).
        int is64 = 1;
        for (int k = 0; k < 64; ++k)
            if ((ei[k] >> 32) != 0ULL) { is64 = 0; break; }
        *flag = is64;
    }
}

// scales + zero the global bucket cursors.
__global__ void k_scales(const float* __restrict__ time_decay,
                         const float* __restrict__ edge_weight,
                         float* __restrict__ step_scale, int num_steps,
                         unsigned int* __restrict__ gcur) {
    int i = threadIdx.x;
    if (i < num_steps) {
        float td = time_decay[i];
        step_scale[i] = edge_weight[i] * expf(-td * td);
    }
    if (i < MAXBINS) gcur[i] = 0u;
}

__global__ void k_init(const float* __restrict__ x, float* __restrict__ cur0,
                       float* __restrict__ surv, int n) {
    int i = blockIdx.x * blockDim.x + threadIdx.x;
    if (i < n) {
        float v = x[i];
        cur0[i] = v;
        surv[i] = 1.0f - v;
    }
}

// Single-pass bucketing: LDS staging, batched cursor reservation,
// per-wave-per-bin flush (no prefix scan, no binary search).
__global__ void k_bucket(const void* __restrict__ ei_raw, const int* __restrict__ flag,
                         const float* __restrict__ probs, unsigned int* __restrict__ gcur,
                         float2* __restrict__ sorted, unsigned int capr,
                         int E, int nbins) {
    __shared__ float2 buf[MAXBINS][STAGE_CAP];
    __shared__ unsigned int cnt[MAXBINS];
    __shared__ unsigned int gbase[MAXBINS];
    const int t = threadIdx.x;
    const int wid = t >> 6, lane = t & 63;
    const int nwaves = BUCKET_TPB / 64;
    const int is64 = *flag;
    const int chunk = (E + gridDim.x - 1) / gridDim.x;
    const int beg = blockIdx.x * chunk;
    const int end = min(E, beg + chunk);
    for (int i = t; i < nbins; i += BUCKET_TPB) cnt[i] = 0u;
    __syncthreads();
    const int ROUND = BUCKET_TPB * BUCKET_K;
    for (int rbeg = beg; rbeg < end; rbeg += ROUND) {
        // ---- insert phase ----
        for (int k = 0; k < BUCKET_K; ++k) {
            int e = rbeg + k * BUCKET_TPB + t;
            if (e < end) {
                int src, dst;
                if (is64) {
                    const long long* s = (const long long*)ei_raw;
                    src = (int)s[e]; dst = (int)s[e + E];
                } else {
                    const int* s = (const int*)ei_raw;
                    src = s[e]; dst = s[e + E];
                }
                float pr = probs[e];
                int bin = dst >> BIN_SHIFT;
                unsigned int payload = (unsigned int)src |
                                       ((unsigned int)(dst & (BIN_SIZE - 1)) << 17);
                unsigned int pos = atomicAdd(&cnt[bin], 1u);
                if (pos < STAGE_CAP) {
                    buf[bin][pos] = make_float2(__uint_as_float(payload), pr);
                } else {
                    // rare overflow: direct per-edge reservation (guarded)
                    unsigned int gp = atomicAdd(&gcur[bin], 1u);
                    if (gp < capr)
                        sorted[(size_t)bin * capr + gp] =
                            make_float2(__uint_as_float(payload), pr);
                }
            }
        }
        __syncthreads();
        // ---- batched reservation: one thread per bin ----
        if (t < nbins) {
            unsigned int c = min(cnt[t], (unsigned int)STAGE_CAP);
            if (c > 0u) gbase[t] = atomicAdd(&gcur[t], c);
        }
        __syncthreads();
        // ---- flush: one bin per wave per iter; lane l writes element l ----
        for (int b = wid; b < nbins; b += nwaves) {
            unsigned int c = min(cnt[b], (unsigned int)STAGE_CAP);
            if ((unsigned int)lane < c) {
                unsigned int gp = gbase[b] + (unsigned int)lane;
                if (gp < capr)
                    sorted[(size_t)b * capr + gp] = buf[b][lane];
            }
        }
        __syncthreads();
        for (int i = t; i < nbins; i += BUCKET_TPB) cnt[i] = 0u;
        __syncthreads();
    }
}

// (bin, split) per block, 1024 threads (16 waves): LDS-accumulate 2048 nodes
// (4-way replicated), write exclusive partial non-atomically.
__global__ void __launch_bounds__(STEP_TPB)
k_step(const float2* __restrict__ sorted, const unsigned int* __restrict__ gcur,
       const float* __restrict__ cur_in, float* __restrict__ part,
       unsigned int capr, int pstride, int nbins, int splits) {
    __shared__ float acc[4][BIN_SIZE];
    const int bin = blockIdx.x / splits;
    const int sp  = blockIdx.x - bin * splits;
    const int t = threadIdx.x;
    float* accf = (float*)acc;
    for (int i = t; i < 4 * BIN_SIZE; i += STEP_TPB) accf[i] = 0.0f;
    __syncthreads();
    unsigned int cntv = min(gcur[bin], capr);
    unsigned int sub = (cntv + (unsigned int)splits - 1) / (unsigned int)splits;
    unsigned int s0 = min(cntv, (unsigned int)sp * sub);
    unsigned int s1 = min(cntv, s0 + sub);
    const float2* base = sorted + (size_t)bin * capr;
    for (unsigned int j = s0 + t; j < s1; j += STEP_TPB) {
        float2 kp = base[j];
        unsigned int v = __float_as_uint(kp.x);
        float m = cur_in[v & 0x1FFFFu] * kp.y;
        atomicAdd(&acc[t & 3][v >> 17], m);
    }
    __syncthreads();
    float* dst = part + (size_t)sp * pstride + (size_t)bin * BIN_SIZE;
    for (int i = t; i < BIN_SIZE; i += STEP_TPB)
        dst[i] = acc[0][i] + acc[1][i] + acc[2][i] + acc[3][i];
}

// Sum partials + fused scale/bias/surv/clip.
__global__ void k_reduce(const float* __restrict__ part, int pstride, int splits,
                         float* __restrict__ cur_out, float* __restrict__ surv,
                         const float* __restrict__ step_scale, const float* __restrict__ bias_p,
                         float* __restrict__ out, int step, int n, int last) {
    int i = blockIdx.x * blockDim.x + threadIdx.x;
    if (i >= n) return;
    float c = 0.0f;
    for (int s = 0; s < splits; ++s) c += part[(size_t)s * pstride + i];
    c = c * step_scale[step] + bias_p[0];
    if (!last) cur_out[i] = c;
    float sv = surv[i] * (1.0f - c);
    surv[i] = sv;
    if (last) out[i] = fminf(fmaxf(1.0f - sv, 0.0f), 1.0f);
}

// --- minimal fallback (ws too small / n too big; not expected) ---
__global__ void k_init0(const float* __restrict__ x, float* __restrict__ cur,
                        float* __restrict__ surv, float* __restrict__ acc, int n) {
    int i = blockIdx.x * blockDim.x + threadIdx.x;
    if (i < n) {
        float v = x[i];
        cur[i] = v; surv[i] = 1.0f - v; acc[i] = 0.0f;
    }
}

__global__ void k_edge_raw(const void* __restrict__ ei_raw, const int* __restrict__ flag,
                           const float* __restrict__ probs, const float* __restrict__ cur,
                           float* __restrict__ acc, const float* __restrict__ step_scale,
                           int step, int num_edges) {
    const float scale = step_scale[step];
    const int is64 = *flag;
    const int stride = gridDim.x * blockDim.x;
    for (int e = blockIdx.x * blockDim.x + threadIdx.x; e < num_edges; e += stride) {
        int src, dst;
        if (is64) {
            const long long* s = (const long long*)ei_raw;
            src = (int)s[e]; dst = (int)s[e + num_edges];
        } else {
            const int* s = (const int*)ei_raw;
            src = s[e]; dst = s[e + num_edges];
        }
        atomicAdd(&acc[dst], cur[src] * (probs[e] * scale));
    }
}

__global__ void k_node(float* __restrict__ cur, float* __restrict__ acc,
                       float* __restrict__ surv, const float* __restrict__ bias_p,
                       float* __restrict__ out, int n, int write_out) {
    int i = blockIdx.x * blockDim.x + threadIdx.x;
    if (i < n) {
        float c = acc[i] + bias_p[0];
        acc[i] = 0.0f;
        cur[i] = c;
        float s = surv[i] * (1.0f - c);
        surv[i] = s;
        if (write_out) out[i] = fminf(fmaxf(1.0f - s, 0.0f), 1.0f);
    }
}

static inline size_t al256(size_t x) { return (x + 255) & ~(size_t)255; }

extern "C" void kernel_launch(void* const* d_in, const int* in_sizes, int n_in,
                              void* d_out, int out_size, void* d_ws, size_t ws_size,
                              hipStream_t stream) {
    const float* x           = (const float*)d_in[0];
    const void*  ei          = d_in[1];
    const float* probs       = (const float*)d_in[2];
    const float* time_decay  = (const float*)d_in[3];
    const float* node_bias   = (const float*)d_in[4];
    const float* edge_weight = (const float*)d_in[5];
    float* outf = (float*)d_out;

    const int n = in_sizes[0];
    const int E = in_sizes[2];
    const int S = in_sizes[3];

    char* ws = (char*)d_ws;
    int*          flag       = (int*)ws;                    // 4B @ 0
    float*        step_scale = (float*)(ws + 64);           // S floats
    unsigned int* gcur       = (unsigned int*)(ws + 256);   // MAXBINS u32

    const int nbins   = (n + BIN_SIZE - 1) >> BIN_SHIFT;
    const int pstride = nbins * BIN_SIZE;

    // Bucket-region capacity: want mean+16sigma, accept down to mean+6sigma.
    const double   meand  = (double)E / (nbins > 0 ? nbins : 1);
    const double   sigma  = sqrt(meand > 1.0 ? meand : 1.0);
    unsigned int   want   = (unsigned int)(meand + 16.0 * sigma + 64.0);
    unsigned int   least  = (unsigned int)(meand + 6.0 * sigma + 64.0);
    want  = (want  + 63u) & ~63u;
    least = (least + 63u) & ~63u;

    const size_t nbA      = al256((size_t)n * 4);
    const size_t off_buf  = 512;
    const size_t off_surv = off_buf + nbA;
    const size_t off_part = al256(off_surv + nbA);

    // Choose largest SPLITS whose layout fits with capr >= least.
    int splits = 0;
    unsigned int capr = 0;
    size_t off_sort = 0;
    const int cand[4] = {8, 6, 5, 4};
    for (int ci = 0; ci < 4; ++ci) {
        int sp = cand[ci];
        size_t part_b = (size_t)sp * pstride * 4;
        size_t osort  = al256(off_part + part_b);
        if (ws_size <= osort) continue;
        size_t availb = ws_size - osort;
        unsigned int acap = (unsigned int)((availb / ((size_t)nbins * 8)) & ~(size_t)63);
        if (acap >= least) {
            splits  = sp;
            capr    = acap < want ? acap : want;
            off_sort = osort;
            break;
        }
    }

    const int nthreads  = 256;
    const int node_grid = (n + nthreads - 1) / nthreads;

    const bool ok = (n <= (1 << 17)) && (nbins >= 1) && (nbins <= MAXBINS) &&
                    (E > 0) && (splits > 0);

    k_detect<<<1, 64, 0, stream>>>((const unsigned long long*)ei, flag);
    k_scales<<<1, 64, 0, stream>>>(time_decay, edge_weight, step_scale, S, gcur);

    if (!ok) {
        // Raw-atomic fallback: cur | surv | acc.
        float* cur  = (float*)(ws + off_buf);
        float* surv = (float*)(ws + off_surv);
        float* acc  = (float*)(ws + off_surv + nbA);
        k_init0<<<node_grid, nthreads, 0, stream>>>(x, cur, surv, acc, n);
        for (int s = 0; s < S; ++s) {
            k_edge_raw<<<2048, nthreads, 0, stream>>>(ei, flag, probs, cur, acc,
                                                      step_scale, s, E);
            k_node<<<node_grid, nthreads, 0, stream>>>(cur, acc, surv, node_bias,
                                                       outf, n, s == S - 1 ? 1 : 0);
        }
        return;
    }

    float*  bufA   = (float*)(ws + off_buf);
    float*  surv   = (float*)(ws + off_surv);
    float*  part   = (float*)(ws + off_part);
    float2* sorted = (float2*)(ws + off_sort);

    // cur ping-pong: last step (s=S-1) must READ a ws buffer.
    float* b0 = (S % 2 == 0) ? outf : bufA;   // cur_in for even s
    float* b1 = (S % 2 == 0) ? bufA : outf;   // cur_in for odd s

    k_init<<<node_grid, nthreads, 0, stream>>>(x, b0, surv, n);

    k_bucket<<<BUCKET_GRID, BUCKET_TPB, 0, stream>>>(ei, flag, probs, gcur, sorted,
                                                     capr, E, nbins);

    const int step_grid = nbins * splits;
    for (int s = 0; s < S; ++s) {
        float* ci = (s % 2 == 0) ? b0 : b1;
        float* co = (s % 2 == 0) ? b1 : b0;
        k_step<<<step_grid, STEP_TPB, 0, stream>>>(sorted, gcur, ci, part,
                                                   capr, pstride, nbins, splits);
        k_reduce<<<node_grid, nthreads, 0, stream>>>(part, pstride, splits, co, surv,
                                                     step_scale, node_bias, outf,
                                                     s, n, s == S - 1 ? 1 : 0);
    }
}